// Round 9
// baseline (2767.422 us; speedup 1.0000x reference)
//
#include <hip/hip_runtime.h>

namespace {

constexpr int NROWS = 256, LSTEPS = 512, IN = 64, LAT = 32, HID = 128;

typedef _Float16 h2 __attribute__((ext_vector_type(2)));
typedef _Float16 h8 __attribute__((ext_vector_type(8)));

__device__ __forceinline__ float fast_sigmoid(float x) {
    return __fdividef(1.f, 1.f + __expf(-x));
}
__device__ __forceinline__ float fast_softplus(float x) {
    return fmaxf(x, 0.f) + __logf(1.f + __expf(-fabsf(x)));
}
__device__ __forceinline__ float fast_tanh(float x) {
    float e = __expf(-2.f * fabsf(x));
    return copysignf(__fdividef(1.f - e, 1.f + e), x);
}
// Unguarded: must lower to v_dot2_f32_f16 (1 VALU per f16-pair MAC).
__device__ __forceinline__ float dot2(h2 w, h2 a, float c) {
    return __builtin_amdgcn_fdot2(w, a, c, false);
}
__device__ __forceinline__ h2 packw(float a, float b) {
    h2 r; r[0] = (_Float16)a; r[1] = (_Float16)b; return r;
}
// LDS-visibility barrier (leave global loads/stores in flight).
__device__ __forceinline__ void soft_barrier() {
    asm volatile("s_waitcnt lgkmcnt(0)\n\ts_barrier" ::: "memory");
}
// Load NB*16B of f16 activations from LDS into h2 pair regs (reused across gates).
template<int NB>
__device__ __forceinline__ void load_acts(const _Float16* p, h2* o) {
#pragma unroll
    for (int i = 0; i < NB; ++i) {
        h8 b = *(const h8*)(p + 8 * i);
        o[4*i+0] = __builtin_shufflevector(b, b, 0, 1);
        o[4*i+1] = __builtin_shufflevector(b, b, 2, 3);
        o[4*i+2] = __builtin_shufflevector(b, b, 4, 5);
        o[4*i+3] = __builtin_shufflevector(b, b, 6, 7);
    }
}
template<int NP>
__device__ __forceinline__ float dotw(const h2* w, const h2* a, float init) {
    float s0 = init, s1 = 0.f, s2 = 0.f, s3 = 0.f;
#pragma unroll
    for (int i = 0; i < NP / 4; ++i) {
        s0 = dot2(w[4*i+0], a[4*i+0], s0);
        s1 = dot2(w[4*i+1], a[4*i+1], s1);
        s2 = dot2(w[4*i+2], a[4*i+2], s2);
        s3 = dot2(w[4*i+3], a[4*i+3], s3);
    }
    return (s0 + s1) + (s2 + s3);
}

} // namespace

// 1024 threads, 1 block/row. Unit-aligned gates, in-wave shfl reduces.
// G-team (t<512): t = 4u+q -> k-quarter q of gh r/z/n for h-unit u (48 h2 regs);
//   lane q==0 owns h_prev (exact f32) and computes the GRU gates.
// H-team (e=t-512): lane8=e&7 -> (mr,kq); xu8=e>>3: pxcz unit; gu=e>>2, c=e&3: gi unit;
//   e<256 additionally qzcx (zu8=e>>3). Phases:
//   A: gh (G) | pxcz_h + qzcx->z (H);  B: next-x write (G) | pxcz_z->x_gen + gi_z (H)
//   D: gh shfl-reduce (G) | gi_x + reduce -> GIR (H);  G: gates (G lane q==0)
__global__ __launch_bounds__(1024) void vrnn_kernel(
    const float* __restrict__ X, const float* __restrict__ EZ, const float* __restrict__ EX,
    const float* __restrict__ Wq, const float* __restrict__ bq,
    const float* __restrict__ Wp, const float* __restrict__ bp,
    const float* __restrict__ Wih, const float* __restrict__ Whh,
    const float* __restrict__ bih, const float* __restrict__ bhh,
    float* __restrict__ out)
{
    __shared__ alignas(16) _Float16 XH[192];   // [ x(64) | h(128) ]
    __shared__ alignas(16) _Float16 ZH[32];    // z_gen
    __shared__ alignas(16) _Float16 XZ[64];    // x_gen
    __shared__ alignas(16) float GIR[128][4];  // gi r/z/n handoff per h-unit

    const int t = threadIdx.x, n = blockIdx.x;
    const bool isG = (t < 512);
    const int e = t - 512;

    // Union weight array (G: [0:48) gh | H: wph[0:16) wpz[16:20) wgx[20:44)
    // wgz[44:56) wq[56:80)) — single array so regalloc doesn't double-count.
    h2 wpk[80];

    float bh0=0,bh1=0,bh2=0,bi0=0,bi1=0,bi2=0;   // G lane q==0
    float bqm=0,bqr=0,bpm=0,bpr=0;               // H lane8==0
    float hprev = 0.f;

    if (isG) {
        const int u = t >> 2, q = t & 3;
#pragma unroll
        for (int g = 0; g < 3; ++g)
#pragma unroll
            for (int p = 0; p < 16; ++p) {
                int k = 32*q + 2*p;
                wpk[g*16+p] = packw(Whh[k*384 + g*128 + u], Whh[(k+1)*384 + g*128 + u]);
            }
        if (q == 0) {
            bh0 = bhh[u]; bh1 = bhh[128+u]; bh2 = bhh[256+u];
            bi0 = bih[u]; bi1 = bih[128+u]; bi2 = bih[256+u];
        }
    } else {
        const int lane8 = e & 7, mr = (e >> 2) & 1, kq = e & 3;
        const int xu8 = e >> 3, gu = e >> 2;
        const int o = xu8 + mr * 64;          // pxcz out col (mean/raw)
#pragma unroll
        for (int p = 0; p < 16; ++p) { int k = 32 + 32*kq + 2*p;   // pxcz h-part
            wpk[p] = packw(Wp[k*128+o], Wp[(k+1)*128+o]); }
#pragma unroll
        for (int p = 0; p < 4; ++p) { int k = 8*kq + 2*p;          // pxcz z-part
            wpk[16+p] = packw(Wp[k*128+o], Wp[(k+1)*128+o]); }
#pragma unroll
        for (int g = 0; g < 3; ++g) {
#pragma unroll
            for (int p = 0; p < 8; ++p) { int k = 16*kq + 2*p;     // gi x-part
                wpk[20+g*8+p] = packw(Wih[k*384+g*128+gu], Wih[(k+1)*384+g*128+gu]); }
#pragma unroll
            for (int p = 0; p < 4; ++p) { int k = 64 + 8*kq + 2*p; // gi z-part
                wpk[44+g*4+p] = packw(Wih[k*384+g*128+gu], Wih[(k+1)*384+g*128+gu]); }
        }
        if (lane8 == 0) { bpm = bp[xu8]; bpr = bp[64+xu8]; }
        if (e < 256) {
            const int zu8 = e >> 3, oq = zu8 + mr*32;              // qzcx out col
#pragma unroll
            for (int p = 0; p < 24; ++p) { int k = 48*kq + 2*p;
                wpk[56+p] = packw(Wq[k*64+oq], Wq[(k+1)*64+oq]); }
            if (lane8 == 0) { bqm = bq[zu8]; bqr = bq[32+zu8]; }
        }
    }

    const float* Xrow = X + (size_t)n * LSTEPS * IN;
    float* orow = out + (size_t)n * LSTEPS * HID + (t >> 2);
    const int ei = isG ? 0 : e;
    const float* ezq = EZ + n*LAT + (ei >> 3);
    const float* exq = EX + n*IN + (ei >> 3);
    float ez=0, ex=0, ezn=0, exn=0, xnA=0, xnB=0;
    if (!isG && e < 256 && (e & 7) == 0) ez = ezq[0];
    if (!isG && (e & 7) == 0) ex = exq[0];
    ezq += NROWS * LAT; exq += NROWS * IN;   // -> l=1
    if (t < 128) XH[64 + t] = (_Float16)0.f;
    if (t < 64) { XH[t] = (_Float16)Xrow[t]; xnA = Xrow[IN + t]; }
    __syncthreads();

    float gh0=0, gh1=0, gh2=0, ph=0, giz0=0, giz1=0, giz2=0;

    for (int l = 0; l < LSTEPS; ++l) {
        // ---- prefetch next-step globals (consumed next iteration) ----
        if (isG) {
            if (t < 64 && l + 2 < LSTEPS) xnB = Xrow[(size_t)(l + 2) * IN + t];
        } else if ((e & 7) == 0) {
            if (l + 1 < LSTEPS) {
                if (e < 256) ezn = ezq[0];
                exn = exq[0];
            }
            ezq += NROWS * LAT; exq += NROWS * IN;
        }

        // ---------------- Phase A ----------------
        if (isG) {
            const int q = t & 3;
            h2 av[16]; load_acts<4>(XH + 64 + 32*q, av);
            gh0 = dotw<16>(wpk +  0, av, 0.f);
            gh1 = dotw<16>(wpk + 16, av, 0.f);
            gh2 = dotw<16>(wpk + 32, av, 0.f);
        } else {
            const int kq = e & 3;
            h2 av[16]; load_acts<4>(XH + 64 + 32*kq, av);
            ph = dotw<16>(wpk, av, 0.f);
            if (e < 256) {
                h2 aq[24]; load_acts<6>(XH + 48*kq, aq);
                float qd = dotw<24>(wpk + 56, aq, 0.f);
                qd += __shfl_xor(qd, 1);
                qd += __shfl_xor(qd, 2);
                float other = __shfl_xor(qd, 4);   // mean <-> raw
                if ((e & 7) == 0) {
                    float z = (qd + bqm) + fast_softplus(other + bqr) * ez;
                    ZH[e >> 3] = (_Float16)z;
                }
            }
        }
        soft_barrier();

        // ---------------- Phase B ----------------
        if (isG) {
            if (t < 64 && l + 1 < LSTEPS) XH[t] = (_Float16)xnA;  // next x
        } else {
            const int kq = e & 3;
            h2 az[4]; load_acts<1>(ZH + 8*kq, az);
            float tot = dotw<4>(wpk + 16, az, ph);
            tot += __shfl_xor(tot, 1);
            tot += __shfl_xor(tot, 2);
            float other = __shfl_xor(tot, 4);      // mean <-> raw
            if ((e & 7) == 0) {
                float xg = (tot + bpm) + fast_softplus(other + bpr) * ex;
                XZ[e >> 3] = (_Float16)xg;
            }
            giz0 = dotw<4>(wpk + 44, az, 0.f);     // gi z-part (same az slice)
            giz1 = dotw<4>(wpk + 48, az, 0.f);
            giz2 = dotw<4>(wpk + 52, az, 0.f);
        }
        soft_barrier();

        // ---------------- Phase D ----------------
        if (isG) {
            gh0 += __shfl_xor(gh0, 1); gh0 += __shfl_xor(gh0, 2);
            gh1 += __shfl_xor(gh1, 1); gh1 += __shfl_xor(gh1, 2);
            gh2 += __shfl_xor(gh2, 1); gh2 += __shfl_xor(gh2, 2);
        } else {
            const int c = e & 3;
            h2 ax[8]; load_acts<2>(XZ + 16*c, ax);
            float g0 = dotw<8>(wpk + 20, ax, giz0);
            float g1 = dotw<8>(wpk + 28, ax, giz1);
            float g2 = dotw<8>(wpk + 36, ax, giz2);
            g0 += __shfl_xor(g0, 1); g0 += __shfl_xor(g0, 2);
            g1 += __shfl_xor(g1, 1); g1 += __shfl_xor(g1, 2);
            g2 += __shfl_xor(g2, 1); g2 += __shfl_xor(g2, 2);
            if (c == 0) {
                float4 v; v.x = g0; v.y = g1; v.z = g2; v.w = 0.f;
                *(float4*)&GIR[e >> 2][0] = v;
            }
        }
        soft_barrier();

        // ---------------- Phase G: gates (G lane q==0) ----------------
        if (isG && (t & 3) == 0) {
            const int u = t >> 2;
            float4 gi = *(const float4*)&GIR[u][0];
            float rr = fast_sigmoid((gi.x + bi0) + (gh0 + bh0));
            float zg = fast_sigmoid((gi.y + bi1) + (gh1 + bh1));
            float nn = fast_tanh(fmaf(rr, gh2 + bh2, gi.z + bi2));
            float h = fmaf(zg, hprev - nn, nn);    // (1-z)*n + z*h
            hprev = h;
            XH[64 + u] = (_Float16)h;
            orow[(size_t)l * HID] = h;
        }
        ez = ezn; ex = exn; xnA = xnB;
        soft_barrier();
    }

    // hs_final[0, n, :]
    if (isG && (t & 3) == 0)
        out[(size_t)NROWS * LSTEPS * HID + (size_t)n * HID + (t >> 2)] = hprev;
}

extern "C" void kernel_launch(void* const* d_in, const int* in_sizes, int n_in,
                              void* d_out, int out_size, void* d_ws, size_t ws_size,
                              hipStream_t stream) {
    const float* X   = (const float*)d_in[0];
    const float* EZ  = (const float*)d_in[1];
    const float* EX  = (const float*)d_in[2];
    const float* Wq  = (const float*)d_in[3];
    const float* bq  = (const float*)d_in[4];
    const float* Wp  = (const float*)d_in[5];
    const float* bp  = (const float*)d_in[6];
    const float* Wih = (const float*)d_in[7];
    const float* Whh = (const float*)d_in[8];
    const float* bih = (const float*)d_in[9];
    const float* bhh = (const float*)d_in[10];
    float* out = (float*)d_out;

    vrnn_kernel<<<dim3(NROWS), dim3(1024), 0, stream>>>(
        X, EZ, EX, Wq, bq, Wp, bp, Wih, Whh, bih, bhh, out);
}